// Round 1
// baseline (131.068 us; speedup 1.0000x reference)
//
#include <hip/hip_runtime.h>

#define NROWS 8192
#define DIM   256

typedef __bf16 bf16x8 __attribute__((ext_vector_type(8)));
typedef __bf16 bf16x4 __attribute__((ext_vector_type(4)));
typedef float  f32x4  __attribute__((ext_vector_type(4)));

typedef __attribute__((address_space(3))) char lds_char;
typedef __attribute__((address_space(1))) const char glob_char;

// Cast x,y (f32) -> bf16 into workspace; compute per-row squared norms.
// One wave per row; lane loads float4 (4 elems), 64 lanes * 4 = 256 = DIM.
__global__ __launch_bounds__(256) void prep_kernel(
    const float* __restrict__ x, const float* __restrict__ y,
    __bf16* __restrict__ xb, __bf16* __restrict__ yb,
    float* __restrict__ x2, float* __restrict__ y2)
{
    int tid  = threadIdx.x;
    int lane = tid & 63;
    int w    = tid >> 6;
    int row  = blockIdx.x * 4 + w;          // 0 .. 16383
    bool isx = row < NROWS;
    int r    = isx ? row : row - NROWS;
    const float* src = (isx ? x : y) + (size_t)r * DIM;
    float4 v = reinterpret_cast<const float4*>(src)[lane];
    float sq = v.x*v.x + v.y*v.y + v.z*v.z + v.w*v.w;
    #pragma unroll
    for (int off = 32; off; off >>= 1) sq += __shfl_xor(sq, off);
    bf16x4 h;
    h[0] = (__bf16)v.x; h[1] = (__bf16)v.y; h[2] = (__bf16)v.z; h[3] = (__bf16)v.w;
    __bf16* dst = (isx ? xb : yb) + (size_t)r * DIM + lane * 4;
    *reinterpret_cast<bf16x4*>(dst) = h;
    if (lane == 0) (isx ? x2 : y2)[r] = sq;
}

__global__ void zero_kernel(float* out) {
    if (threadIdx.x == 0 && blockIdx.x == 0) out[0] = 0.0f;
}

// 128x128 tile, BK=64, 4 waves (2x2), 16x16x32 bf16 MFMA, 4x4 frags/wave.
// LDS: linear dest for global_load_lds; data placed XOR-swizzled via
// pre-swizzled global source; reads apply the same swizzle (rule 21).
__global__ __launch_bounds__(256) void rbf_gemm_kernel(
    const __bf16* __restrict__ xb, const __bf16* __restrict__ yb,
    const float* __restrict__ x2, const float* __restrict__ y2,
    float* __restrict__ out)
{
    __shared__ __bf16 Asm_[128 * 64];   // 16 KB, row stride 128 B
    __shared__ __bf16 Bsm_[128 * 64];   // 16 KB
    __shared__ float  red[4];

    int tid  = threadIdx.x;
    int lane = tid & 63;
    int wv   = tid >> 6;
    int wm   = wv >> 1, wn = wv & 1;    // 2x2 wave grid, 64x64 each
    int bm   = blockIdx.x & 63;
    int bn   = blockIdx.x >> 6;

    f32x4 acc[4][4];
    #pragma unroll
    for (int m = 0; m < 4; ++m)
        #pragma unroll
        for (int n = 0; n < 4; ++n)
            acc[m][n] = (f32x4){0.f, 0.f, 0.f, 0.f};

    int h   = lane >> 4;
    int l15 = lane & 15;

    for (int kt = 0; kt < 4; ++kt) {
        // ---- stage A,B tiles: 4 x global_load_lds(16B) each ----
        #pragma unroll
        for (int i = 0; i < 4; ++i) {
            int lin = i * 4096 + tid * 16;          // linear LDS byte offset
            int row = lin >> 7;                      // /128B per row
            int kb  = lin & 127;
            int kbs = kb ^ ((row & 7) << 4);         // inverse-swizzled source
            size_t gA = (size_t)(bm * 128 + row) * 512 + (size_t)kt * 128 + kbs;
            size_t gB = (size_t)(bn * 128 + row) * 512 + (size_t)kt * 128 + kbs;
            __builtin_amdgcn_global_load_lds(
                (glob_char*)((const char*)xb + gA),
                (lds_char*)((char*)Asm_ + i * 4096 + wv * 1024), 16, 0, 0);
            __builtin_amdgcn_global_load_lds(
                (glob_char*)((const char*)yb + gB),
                (lds_char*)((char*)Bsm_ + i * 4096 + wv * 1024), 16, 0, 0);
        }
        __syncthreads();

        // ---- compute: 2 k-slices x 16 MFMA ----
        #pragma unroll
        for (int kk = 0; kk < 2; ++kk) {
            bf16x8 af[4], bfr[4];
            #pragma unroll
            for (int m = 0; m < 4; ++m) {
                int row = wm * 64 + m * 16 + l15;
                int kb  = (kk * 64 + h * 16) ^ ((row & 7) << 4);
                af[m] = *reinterpret_cast<const bf16x8*>((const char*)Asm_ + row * 128 + kb);
            }
            #pragma unroll
            for (int n = 0; n < 4; ++n) {
                int row = wn * 64 + n * 16 + l15;
                int kb  = (kk * 64 + h * 16) ^ ((row & 7) << 4);
                bfr[n] = *reinterpret_cast<const bf16x8*>((const char*)Bsm_ + row * 128 + kb);
            }
            #pragma unroll
            for (int m = 0; m < 4; ++m)
                #pragma unroll
                for (int n = 0; n < 4; ++n)
                    acc[m][n] = __builtin_amdgcn_mfma_f32_16x16x32_bf16(
                        af[m], bfr[n], acc[m][n], 0, 0, 0);
        }
        __syncthreads();
    }

    // ---- epilogue: d2 = x2 + y2 - 2*dot, k = exp(-d2/2), reduce ----
    // C/D layout (verified): col = lane&15, row = (lane>>4)*4 + reg
    float lsum = 0.f;
    int colbase = bn * 128 + wn * 64 + l15;
    int rowbase = bm * 128 + wm * 64 + h * 4;
    float y2v[4];
    #pragma unroll
    for (int n = 0; n < 4; ++n) y2v[n] = y2[colbase + n * 16];
    #pragma unroll
    for (int m = 0; m < 4; ++m) {
        #pragma unroll
        for (int r = 0; r < 4; ++r) {
            float xr = x2[rowbase + m * 16 + r];
            #pragma unroll
            for (int n = 0; n < 4; ++n) {
                float d2 = fmaf(-2.0f, acc[m][n][r], xr + y2v[n]);
                d2 = fmaxf(d2, 0.0f);
                lsum += exp2f(d2 * -0.7213475204444817f);  // exp(-d2/2)
            }
        }
    }
    #pragma unroll
    for (int off = 32; off; off >>= 1) lsum += __shfl_xor(lsum, off);
    if (lane == 0) red[wv] = lsum;
    __syncthreads();
    if (tid == 0) {
        float s = (red[0] + red[1] + red[2] + red[3]) * 1.4901161193847656e-08f; // /2^26
        atomicAdd(out, s);
    }
}

extern "C" void kernel_launch(void* const* d_in, const int* in_sizes, int n_in,
                              void* d_out, int out_size, void* d_ws, size_t ws_size,
                              hipStream_t stream) {
    const float* x = (const float*)d_in[0];
    const float* y = (const float*)d_in[1];
    float* out = (float*)d_out;
    char* ws = (char*)d_ws;
    __bf16* xb = (__bf16*)ws;                                   // 4 MiB
    __bf16* yb = (__bf16*)(ws + (size_t)4 * 1024 * 1024);       // 4 MiB
    float*  x2 = (float*)(ws + (size_t)8 * 1024 * 1024);        // 32 KiB
    float*  y2 = (float*)(ws + (size_t)8 * 1024 * 1024 + 32 * 1024);

    hipLaunchKernelGGL(zero_kernel, dim3(1), dim3(64), 0, stream, out);
    hipLaunchKernelGGL(prep_kernel, dim3(4096), dim3(256), 0, stream,
                       x, y, xb, yb, x2, y2);
    hipLaunchKernelGGL(rbf_gemm_kernel, dim3(4096), dim3(256), 0, stream,
                       xb, yb, x2, y2, out);
}

// Round 2
// 115.740 us; speedup vs baseline: 1.1324x; 1.1324x over previous
//
#include <hip/hip_runtime.h>

#define NROWS 8192
#define DIM   256

typedef __bf16 bf16x8 __attribute__((ext_vector_type(8)));
typedef __bf16 bf16x4 __attribute__((ext_vector_type(4)));
typedef float  f32x4  __attribute__((ext_vector_type(4)));

typedef __attribute__((address_space(3))) char lds_char;
typedef __attribute__((address_space(1))) const char glob_char;

#define LOG2E  1.4426950408889634f
#define NEG_HALF_LOG2E (-0.7213475204444817f)

// Cast x,y (f32) -> bf16 into workspace; store pre-scaled norms
// px = -||x||^2 * log2(e)/2 so the GEMM epilogue is exp2(fma(dot,log2e,px+py)).
// Also zeroes the output (replaces a separate zero kernel).
__global__ __launch_bounds__(256) void prep_kernel(
    const float* __restrict__ x, const float* __restrict__ y,
    __bf16* __restrict__ xb, __bf16* __restrict__ yb,
    float* __restrict__ px, float* __restrict__ py,
    float* __restrict__ out)
{
    int tid  = threadIdx.x;
    int lane = tid & 63;
    int w    = tid >> 6;
    int row  = blockIdx.x * 4 + w;          // 0 .. 16383
    bool isx = row < NROWS;
    int r    = isx ? row : row - NROWS;
    const float* src = (isx ? x : y) + (size_t)r * DIM;
    float4 v = reinterpret_cast<const float4*>(src)[lane];
    float sq = v.x*v.x + v.y*v.y + v.z*v.z + v.w*v.w;
    #pragma unroll
    for (int off = 32; off; off >>= 1) sq += __shfl_xor(sq, off);
    bf16x4 h;
    h[0] = (__bf16)v.x; h[1] = (__bf16)v.y; h[2] = (__bf16)v.z; h[3] = (__bf16)v.w;
    __bf16* dst = (isx ? xb : yb) + (size_t)r * DIM + lane * 4;
    *reinterpret_cast<bf16x4*>(dst) = h;
    if (lane == 0) (isx ? px : py)[r] = NEG_HALF_LOG2E * sq;
    if (blockIdx.x == 0 && tid == 0) out[0] = 0.0f;
}

// 256x256 tile, 8 waves (2x4), BK=64, double-buffered LDS with 2-phase
// prefetch (issue STAGE(t+1) before compute(t); one vmcnt-drain barrier
// per K-step). LDS linear dest for global_load_lds; XOR swizzle applied
// on the global source and on the ds_read address (rule 21).
__global__ __launch_bounds__(512, 1) void rbf_gemm_kernel(
    const __bf16* __restrict__ xb, const __bf16* __restrict__ yb,
    const float* __restrict__ px, const float* __restrict__ py,
    float* __restrict__ out)
{
    __shared__ char smem[131072];   // 2 bufs x (A 32KB + B 32KB)
    __shared__ float red[8];

    int tid  = threadIdx.x;
    int lane = tid & 63;
    int wv   = tid >> 6;            // 0..7
    int wm   = wv >> 2;             // 0..1 -> 128-row half
    int wn   = wv & 3;              // 0..3 -> 64-col quarter
    int bm   = blockIdx.x & 31;
    int bn   = blockIdx.x >> 5;
    int h    = lane >> 4;
    int l15  = lane & 15;

    f32x4 acc[8][4];
    #pragma unroll
    for (int m = 0; m < 8; ++m)
        #pragma unroll
        for (int n = 0; n < 4; ++n)
            acc[m][n] = (f32x4){0.f, 0.f, 0.f, 0.f};

    auto stage = [&](int buf, int kt) {
        size_t ktoff = (size_t)kt * 128;
        #pragma unroll
        for (int i = 0; i < 4; ++i) {
            int lin = i * 8192 + tid * 16;       // linear LDS byte offset
            int row = lin >> 7;                  // 128 B per row
            int kbs = (lin & 127) ^ ((row & 7) << 4);  // inverse-swizzled src
            size_t gA = (size_t)(bm * 256 + row) * 512 + ktoff + kbs;
            size_t gB = (size_t)(bn * 256 + row) * 512 + ktoff + kbs;
            int ldsoff = buf * 65536 + i * 8192 + wv * 1024;
            __builtin_amdgcn_global_load_lds(
                (glob_char*)((const char*)xb + gA),
                (lds_char*)(smem + ldsoff), 16, 0, 0);
            __builtin_amdgcn_global_load_lds(
                (glob_char*)((const char*)yb + gB),
                (lds_char*)(smem + 32768 + ldsoff), 16, 0, 0);
        }
    };

    auto compute = [&](int buf) {
        const char* Ab = smem + buf * 65536;
        const char* Bb = Ab + 32768;
        #pragma unroll
        for (int kk = 0; kk < 2; ++kk) {
            bf16x8 af[8], bfr[4];
            #pragma unroll
            for (int n = 0; n < 4; ++n) {
                int row = wn * 64 + n * 16 + l15;
                int kb  = (kk * 64 + h * 16) ^ ((row & 7) << 4);
                bfr[n] = *reinterpret_cast<const bf16x8*>(Bb + row * 128 + kb);
            }
            #pragma unroll
            for (int m = 0; m < 8; ++m) {
                int row = wm * 128 + m * 16 + l15;
                int kb  = (kk * 64 + h * 16) ^ ((row & 7) << 4);
                af[m] = *reinterpret_cast<const bf16x8*>(Ab + row * 128 + kb);
            }
            #pragma unroll
            for (int m = 0; m < 8; ++m)
                #pragma unroll
                for (int n = 0; n < 4; ++n)
                    acc[m][n] = __builtin_amdgcn_mfma_f32_16x16x32_bf16(
                        af[m], bfr[n], acc[m][n], 0, 0, 0);
        }
    };

    stage(0, 0);
    __syncthreads();
    #pragma unroll
    for (int kt = 0; kt < 4; ++kt) {
        int cur = kt & 1;
        if (kt < 3) stage(cur ^ 1, kt + 1);   // prefetch next K-tile
        compute(cur);
        __syncthreads();                       // drains vmcnt; next buf ready
    }

    // ---- epilogue: lsum += exp2(fma(dot, log2e, px+py)) ----
    // C/D layout (verified): col = lane&15, row = (lane>>4)*4 + reg
    float lsum = 0.f;
    int colbase = bn * 256 + wn * 64 + l15;
    int rowbase = bm * 256 + wm * 128 + h * 4;
    float py4[4];
    #pragma unroll
    for (int n = 0; n < 4; ++n) py4[n] = py[colbase + n * 16];
    #pragma unroll
    for (int m = 0; m < 8; ++m) {
        #pragma unroll
        for (int r = 0; r < 4; ++r) {
            float pxv = px[rowbase + m * 16 + r];
            #pragma unroll
            for (int n = 0; n < 4; ++n)
                lsum += exp2f(fmaf(acc[m][n][r], LOG2E, pxv + py4[n]));
        }
    }
    #pragma unroll
    for (int off = 32; off; off >>= 1) lsum += __shfl_xor(lsum, off);
    if (lane == 0) red[wv] = lsum;
    __syncthreads();
    if (tid == 0) {
        float s = (red[0] + red[1] + red[2] + red[3] +
                   red[4] + red[5] + red[6] + red[7]) * 1.4901161193847656e-08f;
        atomicAdd(out, s);
    }
}

extern "C" void kernel_launch(void* const* d_in, const int* in_sizes, int n_in,
                              void* d_out, int out_size, void* d_ws, size_t ws_size,
                              hipStream_t stream) {
    const float* x = (const float*)d_in[0];
    const float* y = (const float*)d_in[1];
    float* out = (float*)d_out;
    char* ws = (char*)d_ws;
    __bf16* xb = (__bf16*)ws;                                   // 4 MiB
    __bf16* yb = (__bf16*)(ws + (size_t)4 * 1024 * 1024);       // 4 MiB
    float*  px = (float*)(ws + (size_t)8 * 1024 * 1024);        // 32 KiB
    float*  py = (float*)(ws + (size_t)8 * 1024 * 1024 + 32 * 1024);

    hipLaunchKernelGGL(prep_kernel, dim3(4096), dim3(256), 0, stream,
                       x, y, xb, yb, px, py, out);
    hipLaunchKernelGGL(rbf_gemm_kernel, dim3(1024), dim3(512), 0, stream,
                       xb, yb, px, py, out);
}

// Round 3
// 113.516 us; speedup vs baseline: 1.1546x; 1.0196x over previous
//
#include <hip/hip_runtime.h>

#define NROWS 8192
#define DIM   256

typedef __bf16 bf16x8 __attribute__((ext_vector_type(8)));
typedef __bf16 bf16x4 __attribute__((ext_vector_type(4)));
typedef float  f32x4  __attribute__((ext_vector_type(4)));

typedef __attribute__((address_space(3))) char lds_char;
typedef __attribute__((address_space(1))) const char glob_char;

#define LOG2E  1.4426950408889634f
#define NEG_HALF_LOG2E (-0.7213475204444817f)

#define BAR() asm volatile("s_barrier" ::: "memory")

// Cast x,y (f32) -> bf16; store pre-scaled norms px = -||x||^2 * log2e/2;
// zero the output scalar.
__global__ __launch_bounds__(256) void prep_kernel(
    const float* __restrict__ x, const float* __restrict__ y,
    __bf16* __restrict__ xb, __bf16* __restrict__ yb,
    float* __restrict__ px, float* __restrict__ py,
    float* __restrict__ out)
{
    int tid  = threadIdx.x;
    int lane = tid & 63;
    int w    = tid >> 6;
    int row  = blockIdx.x * 4 + w;          // 0 .. 16383
    bool isx = row < NROWS;
    int r    = isx ? row : row - NROWS;
    const float* src = (isx ? x : y) + (size_t)r * DIM;
    float4 v = reinterpret_cast<const float4*>(src)[lane];
    float sq = v.x*v.x + v.y*v.y + v.z*v.z + v.w*v.w;
    #pragma unroll
    for (int off = 32; off; off >>= 1) sq += __shfl_xor(sq, off);
    bf16x4 h;
    h[0] = (__bf16)v.x; h[1] = (__bf16)v.y; h[2] = (__bf16)v.z; h[3] = (__bf16)v.w;
    __bf16* dst = (isx ? xb : yb) + (size_t)r * DIM + lane * 4;
    *reinterpret_cast<bf16x4*>(dst) = h;
    if (lane == 0) (isx ? px : py)[r] = NEG_HALF_LOG2E * sq;
    if (blockIdx.x == 0 && tid == 0) out[0] = 0.0f;
}

// 256x256 tile, BK=64, 8 waves (2x4), 4-phase-per-K-tile schedule with
// counted vmcnt(8) (T3+T4) + setprio around MFMA clusters (T5).
// LDS: linear dest for global_load_lds, XOR-swizzle on global source and
// on ds_read address (rule 21). Stage units are region-exact 16KB halves:
//   A unit 0 = rows {0-63,128-191}   (m0-3 of both wm)   read only in q0
//   A unit 1 = rows {64-127,192-255} (m4-7)              read only in q2
//   B unit 0 = rows r%64<32  (n0-1 of all wn)            read only in q0
//   B unit 1 = rows r%64>=32 (n2-3)                      read only in q1
// Issue schedule per tile kt (targets tile kt+2, same buffer):
//   q1: A0,B0   q2: B1   q3: A1  -- each one barrier after its region's
// last ds_read, so in-flight writes never touch a region still being read.
__global__ __launch_bounds__(512, 1) void rbf_gemm_kernel(
    const __bf16* __restrict__ xb, const __bf16* __restrict__ yb,
    const float* __restrict__ px, const float* __restrict__ py,
    float* __restrict__ out)
{
    __shared__ char smem[131072];   // 2 bufs x (A 32KB + B 32KB)
    __shared__ float red[8];

    int tid  = threadIdx.x;
    int lane = tid & 63;
    int wv   = tid >> 6;            // 0..7
    int wm   = wv >> 2;             // 0..1 -> 128-row half
    int wn   = wv & 3;              // 0..3 -> 64-col quarter
    int bm   = blockIdx.x & 31;
    int bn   = blockIdx.x >> 5;
    int h    = lane >> 4;
    int l15  = lane & 15;

    f32x4 acc[8][4];
    #pragma unroll
    for (int m = 0; m < 8; ++m)
        #pragma unroll
        for (int n = 0; n < 4; ++n)
            acc[m][n] = (f32x4){0.f, 0.f, 0.f, 0.f};

    // one stage unit = 16KB = 2 x global_load_lds(16B) per thread
    auto stage_unit = [&](int buf, int kt, int matrix, int unit) {
        const __bf16* src = matrix ? yb : xb;
        int baserow = (matrix ? bn : bm) * 256;
        #pragma unroll
        for (int j = 0; j < 2; ++j) {
            int lin = j * 8192 + tid * 16;
            int off;
            if (matrix == 0) off = unit * 8192 + lin + (lin >> 13) * 8192;
            else             off = unit * 4096 + lin + (lin >> 12) * 4096;
            int row = off >> 7;
            int kb  = off & 127;
            int kbs = kb ^ ((row & 7) << 4);
            size_t g = (size_t)(baserow + row) * 512 + (size_t)kt * 128 + kbs;
            __builtin_amdgcn_global_load_lds(
                (glob_char*)((const char*)src + g),
                (lds_char*)(smem + buf * 65536 + matrix * 32768 + off), 16, 0, 0);
        }
    };

    auto ldA = [&](int buf, int mbase, bf16x8* aF) {   // 8 ds_read_b128
        const char* Ab = smem + buf * 65536;
        #pragma unroll
        for (int m = 0; m < 4; ++m)
            #pragma unroll
            for (int kk = 0; kk < 2; ++kk) {
                int row = wm * 128 + (mbase + m) * 16 + l15;
                int kb  = (kk * 64 + h * 16) ^ ((row & 7) << 4);
                aF[m * 2 + kk] = *reinterpret_cast<const bf16x8*>(Ab + row * 128 + kb);
            }
    };
    auto ldB = [&](int buf, int nbase, bf16x8* bF) {   // 4 ds_read_b128
        const char* Bb = smem + buf * 65536 + 32768;
        #pragma unroll
        for (int n = 0; n < 2; ++n)
            #pragma unroll
            for (int kk = 0; kk < 2; ++kk) {
                int row = wn * 64 + (nbase + n) * 16 + l15;
                int kb  = (kk * 64 + h * 16) ^ ((row & 7) << 4);
                bF[n * 2 + kk] = *reinterpret_cast<const bf16x8*>(Bb + row * 128 + kb);
            }
    };
    auto mmaq = [&](int mbase, int nbase, bf16x8* aF, bf16x8* bF) {  // 16 MFMA
        __builtin_amdgcn_s_setprio(1);
        #pragma unroll
        for (int m = 0; m < 4; ++m)
            #pragma unroll
            for (int n = 0; n < 2; ++n)
                #pragma unroll
                for (int kk = 0; kk < 2; ++kk)
                    acc[mbase + m][nbase + n] = __builtin_amdgcn_mfma_f32_16x16x32_bf16(
                        aF[m * 2 + kk], bF[n * 2 + kk], acc[mbase + m][nbase + n], 0, 0, 0);
        __builtin_amdgcn_s_setprio(0);
    };

    // ---- prologue: stage tiles 0 and 1 (16 loads); land tile 0 ----
    stage_unit(0, 0, 0, 0); stage_unit(0, 0, 1, 0);
    stage_unit(0, 0, 1, 1); stage_unit(0, 0, 0, 1);
    stage_unit(1, 1, 0, 0); stage_unit(1, 1, 1, 0);
    stage_unit(1, 1, 1, 1); stage_unit(1, 1, 0, 1);
    asm volatile("s_waitcnt vmcnt(8)" ::: "memory");   // tile0 landed; tile1 in flight
    BAR();

    // ---- main loop: 4 K-tiles x 4 phases ----
    #pragma unroll
    for (int kt = 0; kt < 4; ++kt) {
        int buf = kt & 1;
        bf16x8 aF[8], bF0[4], bF1[4];
        // q0: read A0+B0, MFMA m0-3 x n0-1
        ldA(buf, 0, aF);
        ldB(buf, 0, bF0);
        mmaq(0, 0, aF, bF0);
        BAR();
        // q1: read B1, stage A0+B0 of kt+2, MFMA m0-3 x n2-3
        ldB(buf, 2, bF1);
        if (kt < 2) { stage_unit(buf, kt + 2, 0, 0); stage_unit(buf, kt + 2, 1, 0); }
        mmaq(0, 2, aF, bF1);
        BAR();
        // q2: read A1, stage B1 of kt+2, MFMA m4-7 x n2-3
        ldA(buf, 4, aF);
        if (kt < 2) stage_unit(buf, kt + 2, 1, 1);
        mmaq(4, 2, aF, bF1);
        BAR();
        // q3: stage A1 of kt+2, MFMA m4-7 x n0-1, counted vmcnt, barrier
        if (kt < 2) stage_unit(buf, kt + 2, 0, 1);
        mmaq(4, 0, aF, bF0);
        if (kt < 2)       asm volatile("s_waitcnt vmcnt(8)" ::: "memory");
        else if (kt == 2) asm volatile("s_waitcnt vmcnt(0)" ::: "memory");
        BAR();
    }

    // ---- epilogue: lsum += exp2(fma(dot, log2e, px+py)) ----
    // C/D layout (verified): col = lane&15, row = (lane>>4)*4 + reg
    float lsum = 0.f;
    int colbase = bn * 256 + wn * 64 + l15;
    int rowbase = bm * 256 + wm * 128 + h * 4;
    float py4[4];
    #pragma unroll
    for (int n = 0; n < 4; ++n) py4[n] = py[colbase + n * 16];
    #pragma unroll
    for (int m = 0; m < 8; ++m) {
        #pragma unroll
        for (int r = 0; r < 4; ++r) {
            float pxv = px[rowbase + m * 16 + r];
            #pragma unroll
            for (int n = 0; n < 4; ++n)
                lsum += exp2f(fmaf(acc[m][n][r], LOG2E, pxv + py4[n]));
        }
    }
    #pragma unroll
    for (int off = 32; off; off >>= 1) lsum += __shfl_xor(lsum, off);
    if (lane == 0) red[wv] = lsum;
    __syncthreads();
    if (tid == 0) {
        float s = (red[0] + red[1] + red[2] + red[3] +
                   red[4] + red[5] + red[6] + red[7]) * 1.4901161193847656e-08f;
        atomicAdd(out, s);
    }
}

extern "C" void kernel_launch(void* const* d_in, const int* in_sizes, int n_in,
                              void* d_out, int out_size, void* d_ws, size_t ws_size,
                              hipStream_t stream) {
    const float* x = (const float*)d_in[0];
    const float* y = (const float*)d_in[1];
    float* out = (float*)d_out;
    char* ws = (char*)d_ws;
    __bf16* xb = (__bf16*)ws;                                   // 4 MiB
    __bf16* yb = (__bf16*)(ws + (size_t)4 * 1024 * 1024);       // 4 MiB
    float*  px = (float*)(ws + (size_t)8 * 1024 * 1024);        // 32 KiB
    float*  py = (float*)(ws + (size_t)8 * 1024 * 1024 + 32 * 1024);

    hipLaunchKernelGGL(prep_kernel, dim3(4096), dim3(256), 0, stream,
                       x, y, xb, yb, px, py, out);
    hipLaunchKernelGGL(rbf_gemm_kernel, dim3(1024), dim3(512), 0, stream,
                       xb, yb, px, py, out);
}